// Round 12
// baseline (320.246 us; speedup 1.0000x reference)
//
#include <hip/hip_runtime.h>
#include <math.h>

#define D_ 512
#define K_ 8192
#define N_ 8192
#define KSLICES 16
#define NCAND (KSLICES * 4)    // 64 candidates per row
#define TAU 0.01f

typedef _Float16 f16x8 __attribute__((ext_vector_type(8)));
typedef __attribute__((ext_vector_type(4))) float f32x4;

// ---- x2[n] = np.sum(x*x, axis=1) replicated: numpy pairwise f32 ----
__global__ void x2_kernel(const float* __restrict__ x, float* __restrict__ x2f) {
    int n = blockIdx.x * 64 + threadIdx.x;
    const float* row = &x[(size_t)n * D_];
    float b[4];
    #pragma unroll
    for (int blk = 0; blk < 4; ++blk) {
        const float* a = row + blk * 128;
        float r[8];
        #pragma unroll
        for (int j = 0; j < 8; ++j) { float v = a[j]; r[j] = __fmul_rn(v, v); }
        for (int i = 8; i < 128; i += 8) {
            #pragma unroll
            for (int j = 0; j < 8; ++j) {
                float v = a[i + j];
                r[j] = __fadd_rn(r[j], __fmul_rn(v, v));
            }
        }
        b[blk] = __fadd_rn(__fadd_rn(__fadd_rn(r[0], r[1]), __fadd_rn(r[2], r[3])),
                           __fadd_rn(__fadd_rn(r[4], r[5]), __fadd_rn(r[6], r[7])));
    }
    x2f[n] = __fadd_rn(__fadd_rn(b[0], b[1]), __fadd_rn(b[2], b[3]));
}

// ---- e2[k] = np.sum(e*e, axis=0) replicated: sequential f32 over d ----
__global__ void e2f_kernel(const float* __restrict__ e, float* __restrict__ e2f) {
    int k = blockIdx.x * 64 + threadIdx.x;
    float s = 0.0f;
    #pragma unroll 4
    for (int d = 0; d < D_; ++d) {
        float v = e[(size_t)d * K_ + k];
        s = __fadd_rn(s, __fmul_rn(v, v));
    }
    e2f[k] = s;
}

// ---- x -> fp16, same [N][D] layout ----
__global__ void xcvt_kernel(const float* __restrict__ x, _Float16* __restrict__ xf) {
    size_t i = ((size_t)blockIdx.x * 256 + threadIdx.x) * 8;
    float4 a = *(const float4*)&x[i];
    float4 b = *(const float4*)&x[i + 4];
    f16x8 h;
    h[0] = (_Float16)a.x; h[1] = (_Float16)a.y; h[2] = (_Float16)a.z; h[3] = (_Float16)a.w;
    h[4] = (_Float16)b.x; h[5] = (_Float16)b.y; h[6] = (_Float16)b.z; h[7] = (_Float16)b.w;
    *(f16x8*)&xf[i] = h;
}

// ---- fused e-prep: e -> efT (fp16 [K][D]) AND eT (f32 [K][D]) in one read ----
__global__ void eprep_kernel(const float* __restrict__ e,
                             _Float16* __restrict__ efT, float* __restrict__ eT) {
    __shared__ float t[64][65];
    const int tid = threadIdx.x;
    const int k0 = blockIdx.x * 64;
    const int d0 = blockIdx.y * 64;
    #pragma unroll
    for (int it = 0; it < 4; ++it) {
        int dt = (tid >> 4) + it * 16;
        int c4 = (tid & 15) * 4;
        float4 v = *(const float4*)&e[(size_t)(d0 + dt) * K_ + k0 + c4];
        t[dt][c4 + 0] = v.x; t[dt][c4 + 1] = v.y; t[dt][c4 + 2] = v.z; t[dt][c4 + 3] = v.w;
    }
    __syncthreads();
    const int m = tid >> 2, ch = tid & 3;
    size_t o = (size_t)(k0 + m) * D_ + d0 + ch * 16;
    f16x8 h0, h1;
    #pragma unroll
    for (int j = 0; j < 8; ++j) h0[j] = (_Float16)t[ch * 16 + j][m];
    #pragma unroll
    for (int j = 0; j < 8; ++j) h1[j] = (_Float16)t[ch * 16 + 8 + j][m];
    *(f16x8*)&efT[o] = h0;
    *(f16x8*)&efT[o + 8] = h1;
    #pragma unroll
    for (int j4 = 0; j4 < 4; ++j4) {
        float4 w;
        w.x = t[ch * 16 + j4 * 4 + 0][m];
        w.y = t[ch * 16 + j4 * 4 + 1][m];
        w.z = t[ch * 16 + j4 * 4 + 2][m];
        w.w = t[ch * 16 + j4 * 4 + 3][m];
        *(float4*)&eT[o + j4 * 4] = w;
    }
}

// ---- fp16 MFMA distance pass (reg-staged): top-4 per (row, kslice) ----
// KSLICES=16 -> 1024 blocks, 3 blocks/CU via launch_bounds (LDS 49KB x3 = 147KB).
__launch_bounds__(256, 3)
__global__ void argmin_mfma(const _Float16* __restrict__ xf, const _Float16* __restrict__ efT,
                            const float* __restrict__ x2f, const float* __restrict__ e2f,
                            float* __restrict__ pv4, int* __restrict__ pi4) {
    __shared__ _Float16 XS[2][4096];   // [128 rows][32 d]
    __shared__ _Float16 ES[2][8192];   // [256 codes][32 d]
    __shared__ float e2s[256];

    const int tid = threadIdx.x;
    const int lane = tid & 63;
    const int wid = tid >> 6;
    const int wm = wid & 1, wn = wid >> 1;
    const int lidx = lane & 15, g = lane >> 4;
    const int rowbase = blockIdx.y * 128;
    const int kslice = blockIdx.x;

    float x2r[4];
    #pragma unroll
    for (int nt = 0; nt < 4; ++nt)
        x2r[nt] = x2f[rowbase + (wn << 6) + (nt << 4) + lidx];

    float best[4], sec[4]; int bi[4], si[4];
    #pragma unroll
    for (int nt = 0; nt < 4; ++nt) {
        best[nt] = 3.0e38f; sec[nt] = 3.0e38f; bi[nt] = 0x7ffffffe; si[nt] = 0x7fffffff;
    }

    const int fx0 = tid,       rx0 = fx0 >> 2, cx0 = ((fx0 & 3) - (rx0 >> 1)) & 3;
    const int fx1 = tid + 256, rx1 = fx1 >> 2, cx1 = ((fx1 & 3) - (rx1 >> 1)) & 3;
    const size_t xo0 = (size_t)(rowbase + rx0) * D_ + cx0 * 8;
    const size_t xo1 = (size_t)(rowbase + rx1) * D_ + cx1 * 8;
    int fe[4], re[4], ce[4];
    #pragma unroll
    for (int j = 0; j < 4; ++j) {
        fe[j] = tid + j * 256; re[j] = fe[j] >> 2; ce[j] = ((fe[j] & 3) - (re[j] >> 1)) & 3;
    }

    for (int cc = 0; cc < 2; ++cc) {
        const int codebase = kslice * 512 + cc * 256;
        __syncthreads();
        e2s[tid] = e2f[codebase + tid];

        f32x4 acc[8][4];
        const f32x4 z4 = {0.0f, 0.0f, 0.0f, 0.0f};
        #pragma unroll
        for (int mt = 0; mt < 8; ++mt)
            #pragma unroll
            for (int nt = 0; nt < 4; ++nt) acc[mt][nt] = z4;

        f16x8 st[6];
        st[0] = *(const f16x8*)&xf[xo0];
        st[1] = *(const f16x8*)&xf[xo1];
        #pragma unroll
        for (int j = 0; j < 4; ++j)
            st[2 + j] = *(const f16x8*)&efT[(size_t)(codebase + re[j]) * D_ + ce[j] * 8];
        *(f16x8*)&XS[0][fx0 * 8] = st[0];
        *(f16x8*)&XS[0][fx1 * 8] = st[1];
        #pragma unroll
        for (int j = 0; j < 4; ++j) *(f16x8*)&ES[0][fe[j] * 8] = st[2 + j];
        __syncthreads();

        for (int step = 0; step < 16; ++step) {
            const int cur = step & 1;
            if (step < 15) {
                const int d0 = (step + 1) << 5;
                st[0] = *(const f16x8*)&xf[xo0 + d0];
                st[1] = *(const f16x8*)&xf[xo1 + d0];
                #pragma unroll
                for (int j = 0; j < 4; ++j)
                    st[2 + j] = *(const f16x8*)&efT[(size_t)(codebase + re[j]) * D_ + d0 + ce[j] * 8];
            }
            f16x8 bh[4];
            #pragma unroll
            for (int nt = 0; nt < 4; ++nt) {
                int n = (wn << 6) + (nt << 4) + lidx;
                int sb = (g + (n >> 1)) & 3;
                bh[nt] = *(const f16x8*)&XS[cur][n * 32 + sb * 8];
            }
            #pragma unroll
            for (int mt = 0; mt < 8; ++mt) {
                int m = (wm << 7) + (mt << 4) + lidx;
                int sa = (g + (m >> 1)) & 3;
                f16x8 ah = *(const f16x8*)&ES[cur][m * 32 + sa * 8];
                #pragma unroll
                for (int nt = 0; nt < 4; ++nt)
                    acc[mt][nt] = __builtin_amdgcn_mfma_f32_16x16x32_f16(ah, bh[nt], acc[mt][nt], 0, 0, 0);
            }
            if (step < 15) {
                *(f16x8*)&XS[cur ^ 1][fx0 * 8] = st[0];
                *(f16x8*)&XS[cur ^ 1][fx1 * 8] = st[1];
                #pragma unroll
                for (int j = 0; j < 4; ++j) *(f16x8*)&ES[cur ^ 1][fe[j] * 8] = st[2 + j];
            }
            __syncthreads();
        }

        #pragma unroll
        for (int mt = 0; mt < 8; ++mt) {
            #pragma unroll
            for (int r = 0; r < 4; ++r) {
                const int ml = (wm << 7) + (mt << 4) + (g << 2) + r;
                const float e2k = e2s[ml];
                const int kg = codebase + ml;
                #pragma unroll
                for (int nt = 0; nt < 4; ++nt) {
                    float dot = acc[mt][nt][r];
                    float s = __fsub_rn(__fadd_rn(x2r[nt], e2k), __fmul_rn(2.0f, dot));
                    if (s < best[nt]) {
                        sec[nt] = best[nt]; si[nt] = bi[nt];
                        best[nt] = s; bi[nt] = kg;
                    } else if (s < sec[nt]) {
                        sec[nt] = s; si[nt] = kg;
                    }
                }
            }
        }
    }

    __syncthreads();
    float* entV = (float*)XS;
    int*   entI = (int*)ES;
    #pragma unroll
    for (int nt = 0; nt < 4; ++nt) {
        int rl = (wn << 6) + (nt << 4) + lidx;
        int slot = ((wm << 2) + g) << 1;
        entV[rl * 16 + slot] = best[nt];  entI[rl * 16 + slot] = bi[nt];
        entV[rl * 16 + slot + 1] = sec[nt]; entI[rl * 16 + slot + 1] = si[nt];
    }
    __syncthreads();
    if (tid < 128) {
        float v4[4] = {3.0e38f, 3.0e38f, 3.0e38f, 3.0e38f};
        int i4[4] = {0x7fffffff, 0x7fffffff, 0x7fffffff, 0x7fffffff};
        #pragma unroll
        for (int t2 = 0; t2 < 16; ++t2) {
            float v = entV[tid * 16 + t2]; int i = entI[tid * 16 + t2];
            #pragma unroll
            for (int p = 0; p < 4; ++p) {
                bool better = (v < v4[p]) || (v == v4[p] && i < i4[p]);
                if (better) {
                    float tv = v4[p]; v4[p] = v; v = tv;
                    int ti = i4[p]; i4[p] = i; i = ti;
                }
            }
        }
        size_t o = (size_t)(rowbase + tid) * NCAND + kslice * 4;
        #pragma unroll
        for (int p = 0; p < 4; ++p) { pv4[o + p] = v4[p]; pi4[o + p] = i4[p]; }
    }
}

// ---- reduce top-4 lists -> enc_idx; flag ambiguous rows ----
__global__ void argmin_reduce(const float* __restrict__ pv4, const int* __restrict__ pi4,
                              int* __restrict__ idxbuf, float* __restrict__ out_idx,
                              int* __restrict__ flaglist, unsigned* __restrict__ nflag) {
    int n = blockIdx.x * 256 + threadIdx.x;
    float bv = 3.0e38f, sv = 3.0e38f; int bi = 0x7fffffff;
    for (int j = 0; j < NCAND; ++j) {
        float v = pv4[(size_t)n * NCAND + j]; int i = pi4[(size_t)n * NCAND + j];
        if (v < bv || (v == bv && i < bi)) { sv = bv; bv = v; bi = i; }
        else if (v < sv) sv = v;
    }
    idxbuf[n] = bi;
    out_idx[n] = (float)bi;
    if (sv - bv < TAU) {
        unsigned pos = atomicAdd(nflag, 1u);
        flaglist[pos] = n;
    }
}

// ---- exact refine of flagged rows over their 64 candidates (reads eT, coalesced) ----
__launch_bounds__(256, 2)
__global__ void refine_kernel(const float* __restrict__ x, const float* __restrict__ eT,
                              const float* __restrict__ x2f, const float* __restrict__ e2f,
                              const int* __restrict__ flaglist, const unsigned* __restrict__ nflag,
                              const int* __restrict__ pi4,
                              int* __restrict__ idxbuf, float* __restrict__ out_idx) {
    __shared__ float xrow[D_];
    __shared__ double part[NCAND][4];
    __shared__ int candi[NCAND];
    __shared__ float sv[NCAND];
    const int tid = threadIdx.x;
    const unsigned nf = *nflag;
    for (unsigned f = blockIdx.x; f < nf; f += gridDim.x) {
        const int n = flaglist[f];
        __syncthreads();
        if (tid < NCAND) candi[tid] = pi4[(size_t)n * NCAND + tid];
        for (int d = tid; d < D_; d += 256) xrow[d] = x[(size_t)n * D_ + d];
        __syncthreads();
        const int c = tid >> 2, j = tid & 3;
        const int k = candi[c];
        double a = 0.0;
        #pragma unroll 8
        for (int d = j; d < D_; d += 4)
            a = fma((double)xrow[d], (double)eT[(size_t)k * D_ + d], a);
        part[c][j] = a;
        __syncthreads();
        if (j == 0) {
            double dot = (part[c][0] + part[c][1]) + (part[c][2] + part[c][3]);
            float md = (float)dot;
            sv[c] = __fsub_rn(__fadd_rn(x2f[n], e2f[k]), __fmul_rn(2.0f, md));
        }
        __syncthreads();
        if (tid == 0) {
            float bv = 3.0e38f; int bi = 0x7fffffff;
            for (int c2 = 0; c2 < NCAND; ++c2) {
                float v = sv[c2]; int i2 = candi[c2];
                if (v < bv || (v == bv && i2 < bi)) { bv = v; bi = i2; }
            }
            idxbuf[n] = bi; out_idx[n] = (float)bi;
        }
        __syncthreads();
    }
}

// ---- histogram ----
__global__ void counts_kernel(const int* __restrict__ idxbuf, unsigned* __restrict__ counts) {
    int n = blockIdx.x * 256 + threadIdx.x;
    atomicAdd(&counts[idxbuf[n]], 1u);
}

// ---- exclusive scan of counts -> offsets, cursor (single block) ----
__global__ void scan_kernel(const unsigned* __restrict__ counts,
                            unsigned* __restrict__ offsets, unsigned* __restrict__ cursor) {
    __shared__ unsigned ps[256];
    const int t = threadIdx.x;
    const int base = t * 32;
    unsigned s = 0;
    for (int j = 0; j < 32; ++j) s += counts[base + j];
    ps[t] = s;
    __syncthreads();
    for (int off = 1; off < 256; off <<= 1) {
        unsigned v = (t >= off) ? ps[t - off] : 0u;
        __syncthreads();
        ps[t] += v;
        __syncthreads();
    }
    unsigned run = (t > 0) ? ps[t - 1] : 0u;
    for (int j = 0; j < 32; ++j) {
        int k = base + j;
        offsets[k] = run;
        cursor[k] = run;
        run += counts[k];
    }
}

// ---- fill row lists grouped by code ----
__global__ void fill_kernel(const int* __restrict__ idxbuf, unsigned* __restrict__ cursor,
                            int* __restrict__ rowlist) {
    int n = blockIdx.x * 256 + threadIdx.x;
    int k = idxbuf[n];
    unsigned pos = atomicAdd(&cursor[k], 1u);
    rowlist[pos] = n;
}

// ---- gather quantized (from eT, coalesced) + straight-through + loss partials ----
__global__ void quant_loss_kernel(const float* __restrict__ x, const float* __restrict__ eT,
                                  const int* __restrict__ idxbuf,
                                  float* __restrict__ qout, double* __restrict__ loss_part) {
    int n = blockIdx.x;
    int k = idxbuf[n];
    int d = threadIdx.x * 2;
    float2 q = *(const float2*)&eT[(size_t)k * D_ + d];
    float2 xv = *(const float2*)&x[(size_t)n * D_ + d];
    float2 o;
    float dfx = q.x - xv.x, dfy = q.y - xv.y;
    o.x = xv.x + dfx; o.y = xv.y + dfy;
    *(float2*)&qout[(size_t)n * D_ + d] = o;
    double part = fma((double)dfx, (double)dfx, (double)dfy * (double)dfy);
    __shared__ double sr[256];
    sr[threadIdx.x] = part;
    __syncthreads();
    for (int s = 128; s > 0; s >>= 1) {
        if (threadIdx.x < s) sr[threadIdx.x] += sr[threadIdx.x + s];
        __syncthreads();
    }
    if (threadIdx.x == 0) loss_part[n] = sr[0];
}

// ---- new_cs + perplexity partials ----
__global__ void cs_kernel(const unsigned* __restrict__ counts, const float* __restrict__ cs,
                          float* __restrict__ out_cs,
                          double* __restrict__ ncs_part, double* __restrict__ ent_part) {
    int tid = threadIdx.x;
    int k = blockIdx.x * 256 + tid;
    float cnt = (float)counts[k];
    float ncs = 0.1f * cnt + 0.9f * cs[k];
    out_cs[k] = ncs;
    double p = (double)counts[k] / 8192.0;
    double ent = -p * log(p + 1e-20);

    __shared__ double s1[256], s2[256];
    s1[tid] = (double)ncs;
    s2[tid] = ent;
    __syncthreads();
    for (int s = 128; s > 0; s >>= 1) {
        if (tid < s) { s1[tid] += s1[tid + s]; s2[tid] += s2[tid + s]; }
        __syncthreads();
    }
    if (tid == 0) { ncs_part[blockIdx.x] = s1[0]; ent_part[blockIdx.x] = s2[0]; }
}

// ---- loss, perplexity, nsum ----
__global__ void scalars_kernel(const double* __restrict__ loss_part,
                               const double* __restrict__ ncs_part,
                               const double* __restrict__ ent_part,
                               float* __restrict__ out_loss, float* __restrict__ out_ppl,
                               double* __restrict__ nsum_out) {
    __shared__ double sr[256];
    double s = 0.0;
    for (int i = threadIdx.x; i < N_; i += 256) s += loss_part[i];
    sr[threadIdx.x] = s;
    __syncthreads();
    for (int t = 128; t > 0; t >>= 1) {
        if (threadIdx.x < t) sr[threadIdx.x] += sr[threadIdx.x + t];
        __syncthreads();
    }
    if (threadIdx.x == 0) {
        out_loss[0] = (float)(0.25 * (sr[0] / (double)((size_t)N_ * D_)));
        double nsum = 0.0, ent = 0.0;
        for (int i = 0; i < 32; ++i) { nsum += ncs_part[i]; ent += ent_part[i]; }
        out_ppl[0] = (float)exp(ent);
        nsum_out[0] = nsum;
    }
}

// ---- fused: out_un = 0.9*un + 0.1*gather(x); out_e = out_un / stable_cs ----
__global__ void merge_kernel(const float* __restrict__ x, const float* __restrict__ un,
                             const float* __restrict__ out_cs,
                             const unsigned* __restrict__ offsets, const unsigned* __restrict__ counts,
                             const int* __restrict__ rowlist, const double* __restrict__ nsum,
                             float* __restrict__ out_un, float* __restrict__ out_e) {
    const int f = blockIdx.x * 256 + threadIdx.x;
    const int k = f & (K_ - 1);
    const int d0 = (f >> 13) * 4;
    const unsigned start = offsets[k];
    const unsigned cnt = counts[k];
    float4 s = {0.0f, 0.0f, 0.0f, 0.0f};
    for (unsigned i = 0; i < cnt; ++i) {
        int nr = rowlist[start + i];
        const float4 v = *(const float4*)&x[(size_t)nr * D_ + d0];
        s.x += v.x; s.y += v.y; s.z += v.z; s.w += v.w;
    }
    const double nn = nsum[0];
    const double denom = nn + 8192.0 * 1e-20;
    const float scs = (float)((((double)out_cs[k] + 1e-20) / denom) * nn);
    const float sv[4] = {s.x, s.y, s.z, s.w};
    #pragma unroll
    for (int j = 0; j < 4; ++j) {
        size_t o = (size_t)(d0 + j) * K_ + k;
        float uval = 0.9f * un[o] + 0.1f * sv[j];
        out_un[o] = uval;
        out_e[o] = uval / scs;
    }
}

extern "C" void kernel_launch(void* const* d_in, const int* in_sizes, int n_in,
                              void* d_out, int out_size, void* d_ws, size_t ws_size,
                              hipStream_t stream) {
    const float* x  = (const float*)d_in[0];
    const float* e  = (const float*)d_in[1];
    const float* cs = (const float*)d_in[2];
    const float* un = (const float*)d_in[3];

    float* out = (float*)d_out;
    float* out_q    = out;                    // 4194304
    float* out_loss = out + 4194304;          // 1
    float* out_ppl  = out + 4194305;          // 1
    float* out_idx  = out + 4194306;          // 8192
    float* out_e    = out + 4202498;          // 4194304
    float* out_cs   = out + 8396802;          // 8192
    float* out_un   = out + 8404994;          // 4194304

    // scratch aliases (all consumed before their hosting output is written):
    _Float16* xf16 = (_Float16*)out_q;            // [0, 8MB) of out_q; quant_loss writes out_q later
    float* pv4 = (float*)(out_q + 2097152);       // [8MB,10MB) of out_q; dead after reduce
    int*   pi4 = (int*)(out_q + 2621440);         // [10MB,12MB) of out_q; dead after refine
    _Float16* efT  = (_Float16*)out_e;            // [0, 8MB) of out_e; merge writes out_e last
    float* eT = (float*)out_un;                   // full out_un; read by refine+quant_loss;
                                                  // merge overwrites out_un at the very end

    char* ws = (char*)d_ws;
    unsigned* counts  = (unsigned*)ws;                 // 32768 B  [zeroed]
    unsigned* nflag   = (unsigned*)(ws + 32768);       // 4096 B   [zeroed]
    float* x2f        = (float*)(ws + 36864);          // 32768 B
    float* e2f        = (float*)(ws + 69632);          // 32768 B
    int*   idxbuf     = (int*)(ws + 102400);           // 32768 B
    int*   flaglist   = (int*)(ws + 135168);           // 32768 B
    double* loss_part = (double*)(ws + 167936);        // 65536 B
    double* ncs_part  = (double*)(ws + 233472);        // 256 B
    double* ent_part  = (double*)(ws + 233728);        // 256 B
    double* nsum      = (double*)(ws + 233984);        // 256 B
    unsigned* offsets = (unsigned*)(ws + 234240);      // 32768 B
    unsigned* cursor  = (unsigned*)(ws + 267008);      // 32768 B
    int*   rowlist    = (int*)(ws + 299776);           // 32768 B

    hipMemsetAsync(d_ws, 0, 36864, stream);
    xcvt_kernel<<<2048, 256, 0, stream>>>(x, xf16);
    eprep_kernel<<<dim3(K_ / 64, D_ / 64), 256, 0, stream>>>(e, efT, eT);
    x2_kernel<<<N_ / 64, 64, 0, stream>>>(x, x2f);
    e2f_kernel<<<K_ / 64, 64, 0, stream>>>(e, e2f);
    argmin_mfma<<<dim3(KSLICES, N_ / 128), 256, 0, stream>>>(xf16, efT, x2f, e2f, pv4, pi4);
    argmin_reduce<<<N_ / 256, 256, 0, stream>>>(pv4, pi4, idxbuf, out_idx, flaglist, nflag);
    refine_kernel<<<256, 256, 0, stream>>>(x, eT, x2f, e2f, flaglist, nflag, pi4, idxbuf, out_idx);
    counts_kernel<<<N_ / 256, 256, 0, stream>>>(idxbuf, counts);
    scan_kernel<<<1, 256, 0, stream>>>(counts, offsets, cursor);
    fill_kernel<<<N_ / 256, 256, 0, stream>>>(idxbuf, cursor, rowlist);
    quant_loss_kernel<<<N_, 256, 0, stream>>>(x, eT, idxbuf, out_q, loss_part);
    cs_kernel<<<K_ / 256, 256, 0, stream>>>(counts, cs, out_cs, ncs_part, ent_part);
    scalars_kernel<<<1, 256, 0, stream>>>(loss_part, ncs_part, ent_part, out_loss, out_ppl, nsum);
    merge_kernel<<<K_ * (D_ / 4) / 256, 256, 0, stream>>>(x, un, out_cs, offsets, counts, rowlist, nsum, out_un, out_e);
}

// Round 13
// 259.747 us; speedup vs baseline: 1.2329x; 1.2329x over previous
//
#include <hip/hip_runtime.h>
#include <math.h>

#define D_ 512
#define K_ 8192
#define N_ 8192
#define KSLICES 16
#define NCAND (KSLICES * 4)    // 64 candidates per row
#define TAU 0.01f

typedef _Float16 f16x8 __attribute__((ext_vector_type(8)));
typedef __attribute__((ext_vector_type(4))) float f32x4;

// ---- x2[n] = np.sum(x*x, axis=1) replicated: numpy pairwise f32 ----
__global__ void x2_kernel(const float* __restrict__ x, float* __restrict__ x2f) {
    int n = blockIdx.x * 64 + threadIdx.x;
    const float* row = &x[(size_t)n * D_];
    float b[4];
    #pragma unroll
    for (int blk = 0; blk < 4; ++blk) {
        const float* a = row + blk * 128;
        float r[8];
        #pragma unroll
        for (int j = 0; j < 8; ++j) { float v = a[j]; r[j] = __fmul_rn(v, v); }
        for (int i = 8; i < 128; i += 8) {
            #pragma unroll
            for (int j = 0; j < 8; ++j) {
                float v = a[i + j];
                r[j] = __fadd_rn(r[j], __fmul_rn(v, v));
            }
        }
        b[blk] = __fadd_rn(__fadd_rn(__fadd_rn(r[0], r[1]), __fadd_rn(r[2], r[3])),
                           __fadd_rn(__fadd_rn(r[4], r[5]), __fadd_rn(r[6], r[7])));
    }
    x2f[n] = __fadd_rn(__fadd_rn(b[0], b[1]), __fadd_rn(b[2], b[3]));
}

// ---- e2[k] = np.sum(e*e, axis=0) replicated: sequential f32 over d ----
__global__ void e2f_kernel(const float* __restrict__ e, float* __restrict__ e2f) {
    int k = blockIdx.x * 64 + threadIdx.x;
    float s = 0.0f;
    #pragma unroll 4
    for (int d = 0; d < D_; ++d) {
        float v = e[(size_t)d * K_ + k];
        s = __fadd_rn(s, __fmul_rn(v, v));
    }
    e2f[k] = s;
}

// ---- x -> fp16, same [N][D] layout ----
__global__ void xcvt_kernel(const float* __restrict__ x, _Float16* __restrict__ xf) {
    size_t i = ((size_t)blockIdx.x * 256 + threadIdx.x) * 8;
    float4 a = *(const float4*)&x[i];
    float4 b = *(const float4*)&x[i + 4];
    f16x8 h;
    h[0] = (_Float16)a.x; h[1] = (_Float16)a.y; h[2] = (_Float16)a.z; h[3] = (_Float16)a.w;
    h[4] = (_Float16)b.x; h[5] = (_Float16)b.y; h[6] = (_Float16)b.z; h[7] = (_Float16)b.w;
    *(f16x8*)&xf[i] = h;
}

// ---- fused e-prep: e -> efT (fp16 [K][D]) AND eT (f32 [K][D]) in one read ----
__global__ void eprep_kernel(const float* __restrict__ e,
                             _Float16* __restrict__ efT, float* __restrict__ eT) {
    __shared__ float t[64][65];
    const int tid = threadIdx.x;
    const int k0 = blockIdx.x * 64;
    const int d0 = blockIdx.y * 64;
    #pragma unroll
    for (int it = 0; it < 4; ++it) {
        int dt = (tid >> 4) + it * 16;
        int c4 = (tid & 15) * 4;
        float4 v = *(const float4*)&e[(size_t)(d0 + dt) * K_ + k0 + c4];
        t[dt][c4 + 0] = v.x; t[dt][c4 + 1] = v.y; t[dt][c4 + 2] = v.z; t[dt][c4 + 3] = v.w;
    }
    __syncthreads();
    const int m = tid >> 2, ch = tid & 3;
    size_t o = (size_t)(k0 + m) * D_ + d0 + ch * 16;
    f16x8 h0, h1;
    #pragma unroll
    for (int j = 0; j < 8; ++j) h0[j] = (_Float16)t[ch * 16 + j][m];
    #pragma unroll
    for (int j = 0; j < 8; ++j) h1[j] = (_Float16)t[ch * 16 + 8 + j][m];
    *(f16x8*)&efT[o] = h0;
    *(f16x8*)&efT[o + 8] = h1;
    #pragma unroll
    for (int j4 = 0; j4 < 4; ++j4) {
        float4 w;
        w.x = t[ch * 16 + j4 * 4 + 0][m];
        w.y = t[ch * 16 + j4 * 4 + 1][m];
        w.z = t[ch * 16 + j4 * 4 + 2][m];
        w.w = t[ch * 16 + j4 * 4 + 3][m];
        *(float4*)&eT[o + j4 * 4] = w;
    }
}

// ---- fp16 MFMA distance pass (reg-staged): top-4 per (row, kslice) ----
// KSLICES=16 -> 1024 blocks; launch_bounds(256,2) keeps VGPR=128 (no spill);
// runtime occupancy is LDS-limited at 3 blocks/CU (49KB x 3 = 147KB).
__launch_bounds__(256, 2)
__global__ void argmin_mfma(const _Float16* __restrict__ xf, const _Float16* __restrict__ efT,
                            const float* __restrict__ x2f, const float* __restrict__ e2f,
                            float* __restrict__ pv4, int* __restrict__ pi4) {
    __shared__ _Float16 XS[2][4096];   // [128 rows][32 d]
    __shared__ _Float16 ES[2][8192];   // [256 codes][32 d]
    __shared__ float e2s[256];

    const int tid = threadIdx.x;
    const int lane = tid & 63;
    const int wid = tid >> 6;
    const int wm = wid & 1, wn = wid >> 1;
    const int lidx = lane & 15, g = lane >> 4;
    const int rowbase = blockIdx.y * 128;
    const int kslice = blockIdx.x;

    float x2r[4];
    #pragma unroll
    for (int nt = 0; nt < 4; ++nt)
        x2r[nt] = x2f[rowbase + (wn << 6) + (nt << 4) + lidx];

    float best[4], sec[4]; int bi[4], si[4];
    #pragma unroll
    for (int nt = 0; nt < 4; ++nt) {
        best[nt] = 3.0e38f; sec[nt] = 3.0e38f; bi[nt] = 0x7ffffffe; si[nt] = 0x7fffffff;
    }

    const int fx0 = tid,       rx0 = fx0 >> 2, cx0 = ((fx0 & 3) - (rx0 >> 1)) & 3;
    const int fx1 = tid + 256, rx1 = fx1 >> 2, cx1 = ((fx1 & 3) - (rx1 >> 1)) & 3;
    const size_t xo0 = (size_t)(rowbase + rx0) * D_ + cx0 * 8;
    const size_t xo1 = (size_t)(rowbase + rx1) * D_ + cx1 * 8;
    int fe[4], re[4], ce[4];
    #pragma unroll
    for (int j = 0; j < 4; ++j) {
        fe[j] = tid + j * 256; re[j] = fe[j] >> 2; ce[j] = ((fe[j] & 3) - (re[j] >> 1)) & 3;
    }

    for (int cc = 0; cc < 2; ++cc) {
        const int codebase = kslice * 512 + cc * 256;
        __syncthreads();
        e2s[tid] = e2f[codebase + tid];

        f32x4 acc[8][4];
        const f32x4 z4 = {0.0f, 0.0f, 0.0f, 0.0f};
        #pragma unroll
        for (int mt = 0; mt < 8; ++mt)
            #pragma unroll
            for (int nt = 0; nt < 4; ++nt) acc[mt][nt] = z4;

        f16x8 st[6];
        st[0] = *(const f16x8*)&xf[xo0];
        st[1] = *(const f16x8*)&xf[xo1];
        #pragma unroll
        for (int j = 0; j < 4; ++j)
            st[2 + j] = *(const f16x8*)&efT[(size_t)(codebase + re[j]) * D_ + ce[j] * 8];
        *(f16x8*)&XS[0][fx0 * 8] = st[0];
        *(f16x8*)&XS[0][fx1 * 8] = st[1];
        #pragma unroll
        for (int j = 0; j < 4; ++j) *(f16x8*)&ES[0][fe[j] * 8] = st[2 + j];
        __syncthreads();

        for (int step = 0; step < 16; ++step) {
            const int cur = step & 1;
            if (step < 15) {
                const int d0 = (step + 1) << 5;
                st[0] = *(const f16x8*)&xf[xo0 + d0];
                st[1] = *(const f16x8*)&xf[xo1 + d0];
                #pragma unroll
                for (int j = 0; j < 4; ++j)
                    st[2 + j] = *(const f16x8*)&efT[(size_t)(codebase + re[j]) * D_ + d0 + ce[j] * 8];
            }
            f16x8 bh[4];
            #pragma unroll
            for (int nt = 0; nt < 4; ++nt) {
                int n = (wn << 6) + (nt << 4) + lidx;
                int sb = (g + (n >> 1)) & 3;
                bh[nt] = *(const f16x8*)&XS[cur][n * 32 + sb * 8];
            }
            #pragma unroll
            for (int mt = 0; mt < 8; ++mt) {
                int m = (wm << 7) + (mt << 4) + lidx;
                int sa = (g + (m >> 1)) & 3;
                f16x8 ah = *(const f16x8*)&ES[cur][m * 32 + sa * 8];
                #pragma unroll
                for (int nt = 0; nt < 4; ++nt)
                    acc[mt][nt] = __builtin_amdgcn_mfma_f32_16x16x32_f16(ah, bh[nt], acc[mt][nt], 0, 0, 0);
            }
            if (step < 15) {
                *(f16x8*)&XS[cur ^ 1][fx0 * 8] = st[0];
                *(f16x8*)&XS[cur ^ 1][fx1 * 8] = st[1];
                #pragma unroll
                for (int j = 0; j < 4; ++j) *(f16x8*)&ES[cur ^ 1][fe[j] * 8] = st[2 + j];
            }
            __syncthreads();
        }

        #pragma unroll
        for (int mt = 0; mt < 8; ++mt) {
            #pragma unroll
            for (int r = 0; r < 4; ++r) {
                const int ml = (wm << 7) + (mt << 4) + (g << 2) + r;
                const float e2k = e2s[ml];
                const int kg = codebase + ml;
                #pragma unroll
                for (int nt = 0; nt < 4; ++nt) {
                    float dot = acc[mt][nt][r];
                    float s = __fsub_rn(__fadd_rn(x2r[nt], e2k), __fmul_rn(2.0f, dot));
                    if (s < best[nt]) {
                        sec[nt] = best[nt]; si[nt] = bi[nt];
                        best[nt] = s; bi[nt] = kg;
                    } else if (s < sec[nt]) {
                        sec[nt] = s; si[nt] = kg;
                    }
                }
            }
        }
    }

    __syncthreads();
    float* entV = (float*)XS;
    int*   entI = (int*)ES;
    #pragma unroll
    for (int nt = 0; nt < 4; ++nt) {
        int rl = (wn << 6) + (nt << 4) + lidx;
        int slot = ((wm << 2) + g) << 1;
        entV[rl * 16 + slot] = best[nt];  entI[rl * 16 + slot] = bi[nt];
        entV[rl * 16 + slot + 1] = sec[nt]; entI[rl * 16 + slot + 1] = si[nt];
    }
    __syncthreads();
    if (tid < 128) {
        float v4[4] = {3.0e38f, 3.0e38f, 3.0e38f, 3.0e38f};
        int i4[4] = {0x7fffffff, 0x7fffffff, 0x7fffffff, 0x7fffffff};
        #pragma unroll
        for (int t2 = 0; t2 < 16; ++t2) {
            float v = entV[tid * 16 + t2]; int i = entI[tid * 16 + t2];
            #pragma unroll
            for (int p = 0; p < 4; ++p) {
                bool better = (v < v4[p]) || (v == v4[p] && i < i4[p]);
                if (better) {
                    float tv = v4[p]; v4[p] = v; v = tv;
                    int ti = i4[p]; i4[p] = i; i = ti;
                }
            }
        }
        size_t o = (size_t)(rowbase + tid) * NCAND + kslice * 4;
        #pragma unroll
        for (int p = 0; p < 4; ++p) { pv4[o + p] = v4[p]; pi4[o + p] = i4[p]; }
    }
}

// ---- reduce top-4 lists -> enc_idx; flag ambiguous rows ----
__global__ void argmin_reduce(const float* __restrict__ pv4, const int* __restrict__ pi4,
                              int* __restrict__ idxbuf, float* __restrict__ out_idx,
                              int* __restrict__ flaglist, unsigned* __restrict__ nflag) {
    int n = blockIdx.x * 256 + threadIdx.x;
    float bv = 3.0e38f, sv = 3.0e38f; int bi = 0x7fffffff;
    for (int j = 0; j < NCAND; ++j) {
        float v = pv4[(size_t)n * NCAND + j]; int i = pi4[(size_t)n * NCAND + j];
        if (v < bv || (v == bv && i < bi)) { sv = bv; bv = v; bi = i; }
        else if (v < sv) sv = v;
    }
    idxbuf[n] = bi;
    out_idx[n] = (float)bi;
    if (sv - bv < TAU) {
        unsigned pos = atomicAdd(nflag, 1u);
        flaglist[pos] = n;
    }
}

// ---- exact refine of flagged rows over their 64 candidates (reads eT, coalesced) ----
__launch_bounds__(256, 2)
__global__ void refine_kernel(const float* __restrict__ x, const float* __restrict__ eT,
                              const float* __restrict__ x2f, const float* __restrict__ e2f,
                              const int* __restrict__ flaglist, const unsigned* __restrict__ nflag,
                              const int* __restrict__ pi4,
                              int* __restrict__ idxbuf, float* __restrict__ out_idx) {
    __shared__ float xrow[D_];
    __shared__ double part[NCAND][4];
    __shared__ int candi[NCAND];
    __shared__ float sv[NCAND];
    const int tid = threadIdx.x;
    const unsigned nf = *nflag;
    for (unsigned f = blockIdx.x; f < nf; f += gridDim.x) {
        const int n = flaglist[f];
        __syncthreads();
        if (tid < NCAND) candi[tid] = pi4[(size_t)n * NCAND + tid];
        for (int d = tid; d < D_; d += 256) xrow[d] = x[(size_t)n * D_ + d];
        __syncthreads();
        const int c = tid >> 2, j = tid & 3;
        const int k = candi[c];
        double a = 0.0;
        #pragma unroll 8
        for (int d = j; d < D_; d += 4)
            a = fma((double)xrow[d], (double)eT[(size_t)k * D_ + d], a);
        part[c][j] = a;
        __syncthreads();
        if (j == 0) {
            double dot = (part[c][0] + part[c][1]) + (part[c][2] + part[c][3]);
            float md = (float)dot;
            sv[c] = __fsub_rn(__fadd_rn(x2f[n], e2f[k]), __fmul_rn(2.0f, md));
        }
        __syncthreads();
        if (tid == 0) {
            float bv = 3.0e38f; int bi = 0x7fffffff;
            for (int c2 = 0; c2 < NCAND; ++c2) {
                float v = sv[c2]; int i2 = candi[c2];
                if (v < bv || (v == bv && i2 < bi)) { bv = v; bi = i2; }
            }
            idxbuf[n] = bi; out_idx[n] = (float)bi;
        }
        __syncthreads();
    }
}

// ---- histogram ----
__global__ void counts_kernel(const int* __restrict__ idxbuf, unsigned* __restrict__ counts) {
    int n = blockIdx.x * 256 + threadIdx.x;
    atomicAdd(&counts[idxbuf[n]], 1u);
}

// ---- exclusive scan of counts -> offsets, cursor (single block) ----
__global__ void scan_kernel(const unsigned* __restrict__ counts,
                            unsigned* __restrict__ offsets, unsigned* __restrict__ cursor) {
    __shared__ unsigned ps[256];
    const int t = threadIdx.x;
    const int base = t * 32;
    unsigned s = 0;
    for (int j = 0; j < 32; ++j) s += counts[base + j];
    ps[t] = s;
    __syncthreads();
    for (int off = 1; off < 256; off <<= 1) {
        unsigned v = (t >= off) ? ps[t - off] : 0u;
        __syncthreads();
        ps[t] += v;
        __syncthreads();
    }
    unsigned run = (t > 0) ? ps[t - 1] : 0u;
    for (int j = 0; j < 32; ++j) {
        int k = base + j;
        offsets[k] = run;
        cursor[k] = run;
        run += counts[k];
    }
}

// ---- fill row lists grouped by code ----
__global__ void fill_kernel(const int* __restrict__ idxbuf, unsigned* __restrict__ cursor,
                            int* __restrict__ rowlist) {
    int n = blockIdx.x * 256 + threadIdx.x;
    int k = idxbuf[n];
    unsigned pos = atomicAdd(&cursor[k], 1u);
    rowlist[pos] = n;
}

// ---- gather quantized (from eT, coalesced) + straight-through + loss partials ----
__global__ void quant_loss_kernel(const float* __restrict__ x, const float* __restrict__ eT,
                                  const int* __restrict__ idxbuf,
                                  float* __restrict__ qout, double* __restrict__ loss_part) {
    int n = blockIdx.x;
    int k = idxbuf[n];
    int d = threadIdx.x * 2;
    float2 q = *(const float2*)&eT[(size_t)k * D_ + d];
    float2 xv = *(const float2*)&x[(size_t)n * D_ + d];
    float2 o;
    float dfx = q.x - xv.x, dfy = q.y - xv.y;
    o.x = xv.x + dfx; o.y = xv.y + dfy;
    *(float2*)&qout[(size_t)n * D_ + d] = o;
    double part = fma((double)dfx, (double)dfx, (double)dfy * (double)dfy);
    __shared__ double sr[256];
    sr[threadIdx.x] = part;
    __syncthreads();
    for (int s = 128; s > 0; s >>= 1) {
        if (threadIdx.x < s) sr[threadIdx.x] += sr[threadIdx.x + s];
        __syncthreads();
    }
    if (threadIdx.x == 0) loss_part[n] = sr[0];
}

// ---- new_cs + perplexity partials ----
__global__ void cs_kernel(const unsigned* __restrict__ counts, const float* __restrict__ cs,
                          float* __restrict__ out_cs,
                          double* __restrict__ ncs_part, double* __restrict__ ent_part) {
    int tid = threadIdx.x;
    int k = blockIdx.x * 256 + tid;
    float cnt = (float)counts[k];
    float ncs = 0.1f * cnt + 0.9f * cs[k];
    out_cs[k] = ncs;
    double p = (double)counts[k] / 8192.0;
    double ent = -p * log(p + 1e-20);

    __shared__ double s1[256], s2[256];
    s1[tid] = (double)ncs;
    s2[tid] = ent;
    __syncthreads();
    for (int s = 128; s > 0; s >>= 1) {
        if (tid < s) { s1[tid] += s1[tid + s]; s2[tid] += s2[tid + s]; }
        __syncthreads();
    }
    if (tid == 0) { ncs_part[blockIdx.x] = s1[0]; ent_part[blockIdx.x] = s2[0]; }
}

// ---- loss, perplexity, nsum ----
__global__ void scalars_kernel(const double* __restrict__ loss_part,
                               const double* __restrict__ ncs_part,
                               const double* __restrict__ ent_part,
                               float* __restrict__ out_loss, float* __restrict__ out_ppl,
                               double* __restrict__ nsum_out) {
    __shared__ double sr[256];
    double s = 0.0;
    for (int i = threadIdx.x; i < N_; i += 256) s += loss_part[i];
    sr[threadIdx.x] = s;
    __syncthreads();
    for (int t = 128; t > 0; t >>= 1) {
        if (threadIdx.x < t) sr[threadIdx.x] += sr[threadIdx.x + t];
        __syncthreads();
    }
    if (threadIdx.x == 0) {
        out_loss[0] = (float)(0.25 * (sr[0] / (double)((size_t)N_ * D_)));
        double nsum = 0.0, ent = 0.0;
        for (int i = 0; i < 32; ++i) { nsum += ncs_part[i]; ent += ent_part[i]; }
        out_ppl[0] = (float)exp(ent);
        nsum_out[0] = nsum;
    }
}

// ---- fused: out_un = 0.9*un + 0.1*gather(x); out_e = out_un / stable_cs ----
__global__ void merge_kernel(const float* __restrict__ x, const float* __restrict__ un,
                             const float* __restrict__ out_cs,
                             const unsigned* __restrict__ offsets, const unsigned* __restrict__ counts,
                             const int* __restrict__ rowlist, const double* __restrict__ nsum,
                             float* __restrict__ out_un, float* __restrict__ out_e) {
    const int f = blockIdx.x * 256 + threadIdx.x;
    const int k = f & (K_ - 1);
    const int d0 = (f >> 13) * 4;
    const unsigned start = offsets[k];
    const unsigned cnt = counts[k];
    float4 s = {0.0f, 0.0f, 0.0f, 0.0f};
    for (unsigned i = 0; i < cnt; ++i) {
        int nr = rowlist[start + i];
        const float4 v = *(const float4*)&x[(size_t)nr * D_ + d0];
        s.x += v.x; s.y += v.y; s.z += v.z; s.w += v.w;
    }
    const double nn = nsum[0];
    const double denom = nn + 8192.0 * 1e-20;
    const float scs = (float)((((double)out_cs[k] + 1e-20) / denom) * nn);
    const float sv[4] = {s.x, s.y, s.z, s.w};
    #pragma unroll
    for (int j = 0; j < 4; ++j) {
        size_t o = (size_t)(d0 + j) * K_ + k;
        float uval = 0.9f * un[o] + 0.1f * sv[j];
        out_un[o] = uval;
        out_e[o] = uval / scs;
    }
}

extern "C" void kernel_launch(void* const* d_in, const int* in_sizes, int n_in,
                              void* d_out, int out_size, void* d_ws, size_t ws_size,
                              hipStream_t stream) {
    const float* x  = (const float*)d_in[0];
    const float* e  = (const float*)d_in[1];
    const float* cs = (const float*)d_in[2];
    const float* un = (const float*)d_in[3];

    float* out = (float*)d_out;
    float* out_q    = out;                    // 4194304
    float* out_loss = out + 4194304;          // 1
    float* out_ppl  = out + 4194305;          // 1
    float* out_idx  = out + 4194306;          // 8192
    float* out_e    = out + 4202498;          // 4194304
    float* out_cs   = out + 8396802;          // 8192
    float* out_un   = out + 8404994;          // 4194304

    // scratch aliases (all consumed before their hosting output is written):
    _Float16* xf16 = (_Float16*)out_q;            // [0, 8MB) of out_q; quant_loss writes out_q later
    float* pv4 = (float*)(out_q + 2097152);       // [8MB,10MB) of out_q; dead after reduce
    int*   pi4 = (int*)(out_q + 2621440);         // [10MB,12MB) of out_q; dead after refine
    _Float16* efT  = (_Float16*)out_e;            // [0, 8MB) of out_e; merge writes out_e last
    float* eT = (float*)out_un;                   // full out_un; read by refine+quant_loss;
                                                  // merge overwrites out_un at the very end

    char* ws = (char*)d_ws;
    unsigned* counts  = (unsigned*)ws;                 // 32768 B  [zeroed]
    unsigned* nflag   = (unsigned*)(ws + 32768);       // 4096 B   [zeroed]
    float* x2f        = (float*)(ws + 36864);          // 32768 B
    float* e2f        = (float*)(ws + 69632);          // 32768 B
    int*   idxbuf     = (int*)(ws + 102400);           // 32768 B
    int*   flaglist   = (int*)(ws + 135168);           // 32768 B
    double* loss_part = (double*)(ws + 167936);        // 65536 B
    double* ncs_part  = (double*)(ws + 233472);        // 256 B
    double* ent_part  = (double*)(ws + 233728);        // 256 B
    double* nsum      = (double*)(ws + 233984);        // 256 B
    unsigned* offsets = (unsigned*)(ws + 234240);      // 32768 B
    unsigned* cursor  = (unsigned*)(ws + 267008);      // 32768 B
    int*   rowlist    = (int*)(ws + 299776);           // 32768 B

    hipMemsetAsync(d_ws, 0, 36864, stream);
    xcvt_kernel<<<2048, 256, 0, stream>>>(x, xf16);
    eprep_kernel<<<dim3(K_ / 64, D_ / 64), 256, 0, stream>>>(e, efT, eT);
    x2_kernel<<<N_ / 64, 64, 0, stream>>>(x, x2f);
    e2f_kernel<<<K_ / 64, 64, 0, stream>>>(e, e2f);
    argmin_mfma<<<dim3(KSLICES, N_ / 128), 256, 0, stream>>>(xf16, efT, x2f, e2f, pv4, pi4);
    argmin_reduce<<<N_ / 256, 256, 0, stream>>>(pv4, pi4, idxbuf, out_idx, flaglist, nflag);
    refine_kernel<<<256, 256, 0, stream>>>(x, eT, x2f, e2f, flaglist, nflag, pi4, idxbuf, out_idx);
    counts_kernel<<<N_ / 256, 256, 0, stream>>>(idxbuf, counts);
    scan_kernel<<<1, 256, 0, stream>>>(counts, offsets, cursor);
    fill_kernel<<<N_ / 256, 256, 0, stream>>>(idxbuf, cursor, rowlist);
    quant_loss_kernel<<<N_, 256, 0, stream>>>(x, eT, idxbuf, out_q, loss_part);
    cs_kernel<<<K_ / 256, 256, 0, stream>>>(counts, cs, out_cs, ncs_part, ent_part);
    scalars_kernel<<<1, 256, 0, stream>>>(loss_part, ncs_part, ent_part, out_loss, out_ppl, nsum);
    merge_kernel<<<K_ * (D_ / 4) / 256, 256, 0, stream>>>(x, un, out_cs, offsets, counts, rowlist, nsum, out_un, out_e);
}

// Round 14
// 243.944 us; speedup vs baseline: 1.3128x; 1.0648x over previous
//
#include <hip/hip_runtime.h>
#include <math.h>

#define D_ 512
#define K_ 8192
#define N_ 8192
#define KSLICES 16
#define NCAND (KSLICES * 4)    // 64 candidates per row
#define TAU 0.01f

typedef _Float16 f16x8 __attribute__((ext_vector_type(8)));
typedef __attribute__((ext_vector_type(4))) float f32x4;

// ---- fused x-prep: x -> fp16 (coalesced) AND x2[n] via exact numpy-pairwise tree ----
__global__ void xprep_kernel(const float* __restrict__ x, _Float16* __restrict__ xf,
                             float* __restrict__ x2f) {
    __shared__ float xs[2048];     // 4 rows x 512
    const int tid = threadIdx.x;
    const size_t base = (size_t)blockIdx.x * 2048;
    float4 a = *(const float4*)&x[base + tid * 8];
    float4 b = *(const float4*)&x[base + tid * 8 + 4];
    f16x8 h;
    h[0] = (_Float16)a.x; h[1] = (_Float16)a.y; h[2] = (_Float16)a.z; h[3] = (_Float16)a.w;
    h[4] = (_Float16)b.x; h[5] = (_Float16)b.y; h[6] = (_Float16)b.z; h[7] = (_Float16)b.w;
    *(f16x8*)&xf[base + tid * 8] = h;
    *(float4*)&xs[tid * 8] = a;
    *(float4*)&xs[tid * 8 + 4] = b;
    __syncthreads();
    if (tid < 128) {
        const int l = tid & 63;
        const int row = ((tid >> 6) << 1) + (l >> 5);   // 0..3
        const int c = l & 31;
        const int blk = c >> 3, j = c & 7;
        const float* rb = &xs[row * 512 + blk * 128];
        float v0 = rb[j];
        float r = __fmul_rn(v0, v0);
        for (int i = 8; i < 128; i += 8) {
            float v = rb[i + j];
            r = __fadd_rn(r, __fmul_rn(v, v));
        }
        // exact pairwise tree: ((r0+r1)+(r2+r3))+((r4+r5)+(r6+r7)), then (b0+b1)+(b2+b3)
        r = __fadd_rn(r, __shfl_xor(r, 1));
        r = __fadd_rn(r, __shfl_xor(r, 2));
        r = __fadd_rn(r, __shfl_xor(r, 4));
        r = __fadd_rn(r, __shfl_xor(r, 8));
        r = __fadd_rn(r, __shfl_xor(r, 16));
        if (c == 0) x2f[blockIdx.x * 4 + row] = r;
    }
}

// ---- e2[k] = np.sum(e*e, axis=0) replicated: sequential f32 over d ----
__global__ void e2f_kernel(const float* __restrict__ e, float* __restrict__ e2f) {
    int k = blockIdx.x * 64 + threadIdx.x;
    float s = 0.0f;
    #pragma unroll 4
    for (int d = 0; d < D_; ++d) {
        float v = e[(size_t)d * K_ + k];
        s = __fadd_rn(s, __fmul_rn(v, v));
    }
    e2f[k] = s;
}

// ---- fused e-prep: e -> efT (fp16 [K][D]) AND eT (f32 [K][D]) in one read ----
__global__ void eprep_kernel(const float* __restrict__ e,
                             _Float16* __restrict__ efT, float* __restrict__ eT) {
    __shared__ float t[64][65];
    const int tid = threadIdx.x;
    const int k0 = blockIdx.x * 64;
    const int d0 = blockIdx.y * 64;
    #pragma unroll
    for (int it = 0; it < 4; ++it) {
        int dt = (tid >> 4) + it * 16;
        int c4 = (tid & 15) * 4;
        float4 v = *(const float4*)&e[(size_t)(d0 + dt) * K_ + k0 + c4];
        t[dt][c4 + 0] = v.x; t[dt][c4 + 1] = v.y; t[dt][c4 + 2] = v.z; t[dt][c4 + 3] = v.w;
    }
    __syncthreads();
    const int m = tid >> 2, ch = tid & 3;
    size_t o = (size_t)(k0 + m) * D_ + d0 + ch * 16;
    f16x8 h0, h1;
    #pragma unroll
    for (int j = 0; j < 8; ++j) h0[j] = (_Float16)t[ch * 16 + j][m];
    #pragma unroll
    for (int j = 0; j < 8; ++j) h1[j] = (_Float16)t[ch * 16 + 8 + j][m];
    *(f16x8*)&efT[o] = h0;
    *(f16x8*)&efT[o + 8] = h1;
    #pragma unroll
    for (int j4 = 0; j4 < 4; ++j4) {
        float4 w;
        w.x = t[ch * 16 + j4 * 4 + 0][m];
        w.y = t[ch * 16 + j4 * 4 + 1][m];
        w.z = t[ch * 16 + j4 * 4 + 2][m];
        w.w = t[ch * 16 + j4 * 4 + 3][m];
        *(float4*)&eT[o + j4 * 4] = w;
    }
}

// ---- fp16 MFMA distance pass (reg-staged, 2-unrolled dbuf): top-4 per (row, kslice) ----
__launch_bounds__(256, 2)
__global__ void argmin_mfma(const _Float16* __restrict__ xf, const _Float16* __restrict__ efT,
                            const float* __restrict__ x2f, const float* __restrict__ e2f,
                            float* __restrict__ pv4, int* __restrict__ pi4) {
    __shared__ _Float16 XS[2][4096];   // [128 rows][32 d]
    __shared__ _Float16 ES[2][8192];   // [256 codes][32 d]
    __shared__ float e2s[256];

    const int tid = threadIdx.x;
    const int lane = tid & 63;
    const int wid = tid >> 6;
    const int wm = wid & 1, wn = wid >> 1;
    const int lidx = lane & 15, g = lane >> 4;
    const int rowbase = blockIdx.y * 128;
    const int kslice = blockIdx.x;

    float x2r[4];
    #pragma unroll
    for (int nt = 0; nt < 4; ++nt)
        x2r[nt] = x2f[rowbase + (wn << 6) + (nt << 4) + lidx];

    float best[4], sec[4]; int bi[4], si[4];
    #pragma unroll
    for (int nt = 0; nt < 4; ++nt) {
        best[nt] = 3.0e38f; sec[nt] = 3.0e38f; bi[nt] = 0x7ffffffe; si[nt] = 0x7fffffff;
    }

    const int fx0 = tid,       rx0 = fx0 >> 2, cx0 = ((fx0 & 3) - (rx0 >> 1)) & 3;
    const int fx1 = tid + 256, rx1 = fx1 >> 2, cx1 = ((fx1 & 3) - (rx1 >> 1)) & 3;
    const size_t xo0 = (size_t)(rowbase + rx0) * D_ + cx0 * 8;
    const size_t xo1 = (size_t)(rowbase + rx1) * D_ + cx1 * 8;
    int fe[4], re[4], ce[4];
    #pragma unroll
    for (int j = 0; j < 4; ++j) {
        fe[j] = tid + j * 256; re[j] = fe[j] >> 2; ce[j] = ((fe[j] & 3) - (re[j] >> 1)) & 3;
    }

    for (int cc = 0; cc < 2; ++cc) {
        const int codebase = kslice * 512 + cc * 256;
        __syncthreads();
        e2s[tid] = e2f[codebase + tid];

        f32x4 acc[8][4];
        const f32x4 z4 = {0.0f, 0.0f, 0.0f, 0.0f};
        #pragma unroll
        for (int mt = 0; mt < 8; ++mt)
            #pragma unroll
            for (int nt = 0; nt < 4; ++nt) acc[mt][nt] = z4;

        f16x8 st[6];
        st[0] = *(const f16x8*)&xf[xo0];
        st[1] = *(const f16x8*)&xf[xo1];
        #pragma unroll
        for (int j = 0; j < 4; ++j)
            st[2 + j] = *(const f16x8*)&efT[(size_t)(codebase + re[j]) * D_ + ce[j] * 8];
        *(f16x8*)&XS[0][fx0 * 8] = st[0];
        *(f16x8*)&XS[0][fx1 * 8] = st[1];
        #pragma unroll
        for (int j = 0; j < 4; ++j) *(f16x8*)&ES[0][fe[j] * 8] = st[2 + j];
        __syncthreads();

        // one phase with LITERAL buffer indices (CUR read, NXT written)
        #define STEP_PHASE(CUR, NXT, STEP)                                               \
        {                                                                                \
            if ((STEP) < 15) {                                                           \
                const int dd = ((STEP) + 1) << 5;                                        \
                st[0] = *(const f16x8*)&xf[xo0 + dd];                                    \
                st[1] = *(const f16x8*)&xf[xo1 + dd];                                    \
                _Pragma("unroll")                                                        \
                for (int j = 0; j < 4; ++j)                                              \
                    st[2 + j] = *(const f16x8*)&efT[(size_t)(codebase + re[j]) * D_ + dd + ce[j] * 8]; \
            }                                                                            \
            f16x8 bh[4];                                                                 \
            _Pragma("unroll")                                                            \
            for (int nt = 0; nt < 4; ++nt) {                                             \
                int n = (wn << 6) + (nt << 4) + lidx;                                    \
                int sb = (g + (n >> 1)) & 3;                                             \
                bh[nt] = *(const f16x8*)&XS[CUR][n * 32 + sb * 8];                       \
            }                                                                            \
            _Pragma("unroll")                                                            \
            for (int mt = 0; mt < 8; ++mt) {                                             \
                int m = (wm << 7) + (mt << 4) + lidx;                                    \
                int sa = (g + (m >> 1)) & 3;                                             \
                f16x8 ah = *(const f16x8*)&ES[CUR][m * 32 + sa * 8];                     \
                _Pragma("unroll")                                                        \
                for (int nt = 0; nt < 4; ++nt)                                           \
                    acc[mt][nt] = __builtin_amdgcn_mfma_f32_16x16x32_f16(ah, bh[nt], acc[mt][nt], 0, 0, 0); \
            }                                                                            \
            if ((STEP) < 15) {                                                           \
                *(f16x8*)&XS[NXT][fx0 * 8] = st[0];                                      \
                *(f16x8*)&XS[NXT][fx1 * 8] = st[1];                                      \
                _Pragma("unroll")                                                        \
                for (int j = 0; j < 4; ++j) *(f16x8*)&ES[NXT][fe[j] * 8] = st[2 + j];    \
            }                                                                            \
            __syncthreads();                                                             \
        }

        for (int s2 = 0; s2 < 8; ++s2) {
            STEP_PHASE(0, 1, s2 * 2)
            STEP_PHASE(1, 0, s2 * 2 + 1)
        }
        #undef STEP_PHASE

        #pragma unroll
        for (int mt = 0; mt < 8; ++mt) {
            #pragma unroll
            for (int r = 0; r < 4; ++r) {
                const int ml = (wm << 7) + (mt << 4) + (g << 2) + r;
                const float e2k = e2s[ml];
                const int kg = codebase + ml;
                #pragma unroll
                for (int nt = 0; nt < 4; ++nt) {
                    float dot = acc[mt][nt][r];
                    float s = __fsub_rn(__fadd_rn(x2r[nt], e2k), __fmul_rn(2.0f, dot));
                    if (s < best[nt]) {
                        sec[nt] = best[nt]; si[nt] = bi[nt];
                        best[nt] = s; bi[nt] = kg;
                    } else if (s < sec[nt]) {
                        sec[nt] = s; si[nt] = kg;
                    }
                }
            }
        }
    }

    __syncthreads();
    float* entV = (float*)XS;
    int*   entI = (int*)ES;
    #pragma unroll
    for (int nt = 0; nt < 4; ++nt) {
        int rl = (wn << 6) + (nt << 4) + lidx;
        int slot = ((wm << 2) + g) << 1;
        entV[rl * 16 + slot] = best[nt];  entI[rl * 16 + slot] = bi[nt];
        entV[rl * 16 + slot + 1] = sec[nt]; entI[rl * 16 + slot + 1] = si[nt];
    }
    __syncthreads();
    if (tid < 128) {
        float v4[4] = {3.0e38f, 3.0e38f, 3.0e38f, 3.0e38f};
        int i4[4] = {0x7fffffff, 0x7fffffff, 0x7fffffff, 0x7fffffff};
        #pragma unroll
        for (int t2 = 0; t2 < 16; ++t2) {
            float v = entV[tid * 16 + t2]; int i = entI[tid * 16 + t2];
            #pragma unroll
            for (int p = 0; p < 4; ++p) {
                bool better = (v < v4[p]) || (v == v4[p] && i < i4[p]);
                if (better) {
                    float tv = v4[p]; v4[p] = v; v = tv;
                    int ti = i4[p]; i4[p] = i; i = ti;
                }
            }
        }
        size_t o = (size_t)(rowbase + tid) * NCAND + kslice * 4;
        #pragma unroll
        for (int p = 0; p < 4; ++p) { pv4[o + p] = v4[p]; pi4[o + p] = i4[p]; }
    }
}

// ---- reduce top-4 lists -> enc_idx; flag ambiguous rows; count unflagged ----
__global__ void argmin_reduce(const float* __restrict__ pv4, const int* __restrict__ pi4,
                              int* __restrict__ idxbuf, float* __restrict__ out_idx,
                              int* __restrict__ flaglist, unsigned* __restrict__ nflag,
                              unsigned* __restrict__ counts) {
    int n = blockIdx.x * 256 + threadIdx.x;
    float bv = 3.0e38f, sv = 3.0e38f; int bi = 0x7fffffff;
    for (int j = 0; j < NCAND; ++j) {
        float v = pv4[(size_t)n * NCAND + j]; int i = pi4[(size_t)n * NCAND + j];
        if (v < bv || (v == bv && i < bi)) { sv = bv; bv = v; bi = i; }
        else if (v < sv) sv = v;
    }
    idxbuf[n] = bi;
    out_idx[n] = (float)bi;
    if (sv - bv < TAU) {
        unsigned pos = atomicAdd(nflag, 1u);
        flaglist[pos] = n;
    } else {
        atomicAdd(&counts[bi], 1u);
    }
}

// ---- exact refine of flagged rows over their 64 candidates; counts final choice ----
__launch_bounds__(256, 2)
__global__ void refine_kernel(const float* __restrict__ x, const float* __restrict__ eT,
                              const float* __restrict__ x2f, const float* __restrict__ e2f,
                              const int* __restrict__ flaglist, const unsigned* __restrict__ nflag,
                              const int* __restrict__ pi4,
                              int* __restrict__ idxbuf, float* __restrict__ out_idx,
                              unsigned* __restrict__ counts) {
    __shared__ float xrow[D_];
    __shared__ double part[NCAND][4];
    __shared__ int candi[NCAND];
    __shared__ float sv[NCAND];
    const int tid = threadIdx.x;
    const unsigned nf = *nflag;
    for (unsigned f = blockIdx.x; f < nf; f += gridDim.x) {
        const int n = flaglist[f];
        __syncthreads();
        if (tid < NCAND) candi[tid] = pi4[(size_t)n * NCAND + tid];
        for (int d = tid; d < D_; d += 256) xrow[d] = x[(size_t)n * D_ + d];
        __syncthreads();
        const int c = tid >> 2, j = tid & 3;
        const int k = candi[c];
        double a = 0.0;
        #pragma unroll 8
        for (int d = j; d < D_; d += 4)
            a = fma((double)xrow[d], (double)eT[(size_t)k * D_ + d], a);
        part[c][j] = a;
        __syncthreads();
        if (j == 0) {
            double dot = (part[c][0] + part[c][1]) + (part[c][2] + part[c][3]);
            float md = (float)dot;
            sv[c] = __fsub_rn(__fadd_rn(x2f[n], e2f[k]), __fmul_rn(2.0f, md));
        }
        __syncthreads();
        if (tid == 0) {
            float bv = 3.0e38f; int bi = 0x7fffffff;
            for (int c2 = 0; c2 < NCAND; ++c2) {
                float v = sv[c2]; int i2 = candi[c2];
                if (v < bv || (v == bv && i2 < bi)) { bv = v; bi = i2; }
            }
            idxbuf[n] = bi; out_idx[n] = (float)bi;
            atomicAdd(&counts[bi], 1u);
        }
        __syncthreads();
    }
}

// ---- exclusive scan of counts -> offsets, cursor (single block) ----
__global__ void scan_kernel(const unsigned* __restrict__ counts,
                            unsigned* __restrict__ offsets, unsigned* __restrict__ cursor) {
    __shared__ unsigned ps[256];
    const int t = threadIdx.x;
    const int base = t * 32;
    unsigned s = 0;
    for (int j = 0; j < 32; ++j) s += counts[base + j];
    ps[t] = s;
    __syncthreads();
    for (int off = 1; off < 256; off <<= 1) {
        unsigned v = (t >= off) ? ps[t - off] : 0u;
        __syncthreads();
        ps[t] += v;
        __syncthreads();
    }
    unsigned run = (t > 0) ? ps[t - 1] : 0u;
    for (int j = 0; j < 32; ++j) {
        int k = base + j;
        offsets[k] = run;
        cursor[k] = run;
        run += counts[k];
    }
}

// ---- fill row lists grouped by code ----
__global__ void fill_kernel(const int* __restrict__ idxbuf, unsigned* __restrict__ cursor,
                            int* __restrict__ rowlist) {
    int n = blockIdx.x * 256 + threadIdx.x;
    int k = idxbuf[n];
    unsigned pos = atomicAdd(&cursor[k], 1u);
    rowlist[pos] = n;
}

// ---- gather quantized (from eT, coalesced) + straight-through + loss partials ----
__global__ void quant_loss_kernel(const float* __restrict__ x, const float* __restrict__ eT,
                                  const int* __restrict__ idxbuf,
                                  float* __restrict__ qout, double* __restrict__ loss_part) {
    int n = blockIdx.x;
    int k = idxbuf[n];
    int d = threadIdx.x * 2;
    float2 q = *(const float2*)&eT[(size_t)k * D_ + d];
    float2 xv = *(const float2*)&x[(size_t)n * D_ + d];
    float2 o;
    float dfx = q.x - xv.x, dfy = q.y - xv.y;
    o.x = xv.x + dfx; o.y = xv.y + dfy;
    *(float2*)&qout[(size_t)n * D_ + d] = o;
    double part = fma((double)dfx, (double)dfx, (double)dfy * (double)dfy);
    __shared__ double sr[256];
    sr[threadIdx.x] = part;
    __syncthreads();
    for (int s = 128; s > 0; s >>= 1) {
        if (threadIdx.x < s) sr[threadIdx.x] += sr[threadIdx.x + s];
        __syncthreads();
    }
    if (threadIdx.x == 0) loss_part[n] = sr[0];
}

// ---- new_cs + perplexity partials ----
__global__ void cs_kernel(const unsigned* __restrict__ counts, const float* __restrict__ cs,
                          float* __restrict__ out_cs,
                          double* __restrict__ ncs_part, double* __restrict__ ent_part) {
    int tid = threadIdx.x;
    int k = blockIdx.x * 256 + tid;
    float cnt = (float)counts[k];
    float ncs = 0.1f * cnt + 0.9f * cs[k];
    out_cs[k] = ncs;
    double p = (double)counts[k] / 8192.0;
    double ent = -p * log(p + 1e-20);

    __shared__ double s1[256], s2[256];
    s1[tid] = (double)ncs;
    s2[tid] = ent;
    __syncthreads();
    for (int s = 128; s > 0; s >>= 1) {
        if (tid < s) { s1[tid] += s1[tid + s]; s2[tid] += s2[tid + s]; }
        __syncthreads();
    }
    if (tid == 0) { ncs_part[blockIdx.x] = s1[0]; ent_part[blockIdx.x] = s2[0]; }
}

// ---- loss, perplexity, nsum ----
__global__ void scalars_kernel(const double* __restrict__ loss_part,
                               const double* __restrict__ ncs_part,
                               const double* __restrict__ ent_part,
                               float* __restrict__ out_loss, float* __restrict__ out_ppl,
                               double* __restrict__ nsum_out) {
    __shared__ double sr[256];
    double s = 0.0;
    for (int i = threadIdx.x; i < N_; i += 256) s += loss_part[i];
    sr[threadIdx.x] = s;
    __syncthreads();
    for (int t = 128; t > 0; t >>= 1) {
        if (threadIdx.x < t) sr[threadIdx.x] += sr[threadIdx.x + t];
        __syncthreads();
    }
    if (threadIdx.x == 0) {
        out_loss[0] = (float)(0.25 * (sr[0] / (double)((size_t)N_ * D_)));
        double nsum = 0.0, ent = 0.0;
        for (int i = 0; i < 32; ++i) { nsum += ncs_part[i]; ent += ent_part[i]; }
        out_ppl[0] = (float)exp(ent);
        nsum_out[0] = nsum;
    }
}

// ---- fused: out_un = 0.9*un + 0.1*gather(x); out_e = out_un / stable_cs ----
__global__ void merge_kernel(const float* __restrict__ x, const float* __restrict__ un,
                             const float* __restrict__ out_cs,
                             const unsigned* __restrict__ offsets, const unsigned* __restrict__ counts,
                             const int* __restrict__ rowlist, const double* __restrict__ nsum,
                             float* __restrict__ out_un, float* __restrict__ out_e) {
    const int f = blockIdx.x * 256 + threadIdx.x;
    const int k = f & (K_ - 1);
    const int d0 = (f >> 13) * 4;
    const unsigned start = offsets[k];
    const unsigned cnt = counts[k];
    float4 s = {0.0f, 0.0f, 0.0f, 0.0f};
    for (unsigned i = 0; i < cnt; ++i) {
        int nr = rowlist[start + i];
        const float4 v = *(const float4*)&x[(size_t)nr * D_ + d0];
        s.x += v.x; s.y += v.y; s.z += v.z; s.w += v.w;
    }
    const double nn = nsum[0];
    const double denom = nn + 8192.0 * 1e-20;
    const float scs = (float)((((double)out_cs[k] + 1e-20) / denom) * nn);
    const float sv[4] = {s.x, s.y, s.z, s.w};
    #pragma unroll
    for (int j = 0; j < 4; ++j) {
        size_t o = (size_t)(d0 + j) * K_ + k;
        float uval = 0.9f * un[o] + 0.1f * sv[j];
        out_un[o] = uval;
        out_e[o] = uval / scs;
    }
}

extern "C" void kernel_launch(void* const* d_in, const int* in_sizes, int n_in,
                              void* d_out, int out_size, void* d_ws, size_t ws_size,
                              hipStream_t stream) {
    const float* x  = (const float*)d_in[0];
    const float* e  = (const float*)d_in[1];
    const float* cs = (const float*)d_in[2];
    const float* un = (const float*)d_in[3];

    float* out = (float*)d_out;
    float* out_q    = out;                    // 4194304
    float* out_loss = out + 4194304;          // 1
    float* out_ppl  = out + 4194305;          // 1
    float* out_idx  = out + 4194306;          // 8192
    float* out_e    = out + 4202498;          // 4194304
    float* out_cs   = out + 8396802;          // 8192
    float* out_un   = out + 8404994;          // 4194304

    // scratch aliases (all consumed before their hosting output is written):
    _Float16* xf16 = (_Float16*)out_q;            // [0, 8MB) of out_q; quant_loss writes out_q later
    float* pv4 = (float*)(out_q + 2097152);       // [8MB,10MB) of out_q; dead after reduce
    int*   pi4 = (int*)(out_q + 2621440);         // [10MB,12MB) of out_q; dead after refine
    _Float16* efT  = (_Float16*)out_e;            // [0, 8MB) of out_e; merge writes out_e last
    float* eT = (float*)out_un;                   // full out_un; read by refine+quant_loss;
                                                  // merge overwrites out_un at the very end

    char* ws = (char*)d_ws;
    unsigned* counts  = (unsigned*)ws;                 // 32768 B  [zeroed]
    unsigned* nflag   = (unsigned*)(ws + 32768);       // 4096 B   [zeroed]
    float* x2f        = (float*)(ws + 36864);          // 32768 B
    float* e2f        = (float*)(ws + 69632);          // 32768 B
    int*   idxbuf     = (int*)(ws + 102400);           // 32768 B
    int*   flaglist   = (int*)(ws + 135168);           // 32768 B
    double* loss_part = (double*)(ws + 167936);        // 65536 B
    double* ncs_part  = (double*)(ws + 233472);        // 256 B
    double* ent_part  = (double*)(ws + 233728);        // 256 B
    double* nsum      = (double*)(ws + 233984);        // 256 B
    unsigned* offsets = (unsigned*)(ws + 234240);      // 32768 B
    unsigned* cursor  = (unsigned*)(ws + 267008);      // 32768 B
    int*   rowlist    = (int*)(ws + 299776);           // 32768 B

    hipMemsetAsync(d_ws, 0, 36864, stream);
    xprep_kernel<<<2048, 256, 0, stream>>>(x, xf16, x2f);
    eprep_kernel<<<dim3(K_ / 64, D_ / 64), 256, 0, stream>>>(e, efT, eT);
    e2f_kernel<<<K_ / 64, 64, 0, stream>>>(e, e2f);
    argmin_mfma<<<dim3(KSLICES, N_ / 128), 256, 0, stream>>>(xf16, efT, x2f, e2f, pv4, pi4);
    argmin_reduce<<<N_ / 256, 256, 0, stream>>>(pv4, pi4, idxbuf, out_idx, flaglist, nflag, counts);
    refine_kernel<<<256, 256, 0, stream>>>(x, eT, x2f, e2f, flaglist, nflag, pi4, idxbuf, out_idx, counts);
    scan_kernel<<<1, 256, 0, stream>>>(counts, offsets, cursor);
    fill_kernel<<<N_ / 256, 256, 0, stream>>>(idxbuf, cursor, rowlist);
    quant_loss_kernel<<<N_, 256, 0, stream>>>(x, eT, idxbuf, out_q, loss_part);
    cs_kernel<<<K_ / 256, 256, 0, stream>>>(counts, cs, out_cs, ncs_part, ent_part);
    scalars_kernel<<<1, 256, 0, stream>>>(loss_part, ncs_part, ent_part, out_loss, out_ppl, nsum);
    merge_kernel<<<K_ * (D_ / 4) / 256, 256, 0, stream>>>(x, un, out_cs, offsets, counts, rowlist, nsum, out_un, out_e);
}